// Round 1
// baseline (149.075 us; speedup 1.0000x reference)
//
#include <hip/hip_runtime.h>
#include <hip/hip_bf16.h>

typedef __bf16 bf16x8 __attribute__((ext_vector_type(8)));
typedef float f32x4 __attribute__((ext_vector_type(4)));

#define HEADS 12
#define DDIM 64
#define LSEQ 512
#define BATCH 16
#define HID 768
#define NOUT 1536   // HEADS * 2 * DDIM
#define BIG_NEG 1000000000000.0f

// ---------------- kernel 1: RoPE cos/sin table (512 x 64 float2) -------------
__global__ void rope_tab_k(float2* __restrict__ tab) {
    int idx = blockIdx.x * 256 + threadIdx.x;
    if (idx >= LSEQ * DDIM) return;
    int l = idx >> 6, d = idx & 63;
    int p = d >> 1;
    float inv = powf(10000.0f, (-2.0f * (float)p) / 64.0f);
    float ang = (float)l * inv;
    tab[idx] = make_float2(cosf(ang), sinf(ang));
}

// ---------------- kernel 2: proj GEMM + bias + RoPE -> bf16 q/k slabs --------
// X: (8192, 768) f32, W: (768, 1536) f32, out tile 128x128, 4 waves (2x2 of 64x64)
__global__ __launch_bounds__(256) void proj_rope_k(
    const float* __restrict__ X, const float* __restrict__ W,
    const float* __restrict__ bias, const float2* __restrict__ tab,
    __bf16* __restrict__ qws, __bf16* __restrict__ kws) {

    __shared__ __bf16 As[128][40];   // [m][k], stride 40 keeps 16B align + 2-way banks
    __shared__ __bf16 Bs[128][40];   // [n][k] (transposed W tile)

    const int tid  = threadIdx.x;
    const int m0   = blockIdx.x * 128;
    const int n0   = blockIdx.y * 128;
    const int wid  = tid >> 6, lane = tid & 63;
    const int wm   = wid >> 1, wn = wid & 1;
    const int lr   = lane & 15;          // fragment row/col within 16
    const int kg   = lane >> 4;          // k-group 0..3
    const int lk   = kg * 8;             // k offset of this lane's 8 elems

    // staging assignments
    const int ar = tid >> 1, ac = (tid & 1) * 16;   // A: 128 rows x 32 k
    const int bk = tid >> 3, bn = (tid & 7) * 16;   // B: 32 k-rows x 128 n

    f32x4 acc[4][4] = {};

    for (int k0 = 0; k0 < HID; k0 += 32) {
        // ---- stage A (fp32 -> bf16) ----
        const float* aptr = X + (size_t)(m0 + ar) * HID + k0 + ac;
        float4 a0 = *(const float4*)(aptr + 0);
        float4 a1 = *(const float4*)(aptr + 4);
        float4 a2 = *(const float4*)(aptr + 8);
        float4 a3 = *(const float4*)(aptr + 12);
        bf16x8 pa0 = { (__bf16)a0.x,(__bf16)a0.y,(__bf16)a0.z,(__bf16)a0.w,
                       (__bf16)a1.x,(__bf16)a1.y,(__bf16)a1.z,(__bf16)a1.w };
        bf16x8 pa1 = { (__bf16)a2.x,(__bf16)a2.y,(__bf16)a2.z,(__bf16)a2.w,
                       (__bf16)a3.x,(__bf16)a3.y,(__bf16)a3.z,(__bf16)a3.w };

        // ---- stage B (fp32 -> bf16, transposed into [n][k]) ----
        const float* bptr = W + (size_t)(k0 + bk) * NOUT + n0 + bn;
        float4 b0 = *(const float4*)(bptr + 0);
        float4 b1 = *(const float4*)(bptr + 4);
        float4 b2 = *(const float4*)(bptr + 8);
        float4 b3 = *(const float4*)(bptr + 12);
        float bv[16] = { b0.x,b0.y,b0.z,b0.w, b1.x,b1.y,b1.z,b1.w,
                         b2.x,b2.y,b2.z,b2.w, b3.x,b3.y,b3.z,b3.w };

        *(bf16x8*)&As[ar][ac]     = pa0;
        *(bf16x8*)&As[ar][ac + 8] = pa1;
#pragma unroll
        for (int i = 0; i < 16; ++i) Bs[bn + i][bk] = (__bf16)bv[i];

        __syncthreads();

        bf16x8 af[4], bfr[4];
#pragma unroll
        for (int mi = 0; mi < 4; ++mi)
            af[mi] = *(bf16x8*)&As[wm * 64 + mi * 16 + lr][lk];
#pragma unroll
        for (int ni = 0; ni < 4; ++ni)
            bfr[ni] = *(bf16x8*)&Bs[wn * 64 + ni * 16 + lr][lk];
#pragma unroll
        for (int mi = 0; mi < 4; ++mi)
#pragma unroll
            for (int ni = 0; ni < 4; ++ni)
                acc[mi][ni] = __builtin_amdgcn_mfma_f32_16x16x32_bf16(
                    af[mi], bfr[ni], acc[mi][ni], 0, 0, 0);

        __syncthreads();
    }

    // ---- epilogue: bias + RoPE, write bf16 Q/K slabs [B][H][L][D] ----
#pragma unroll
    for (int ni = 0; ni < 4; ++ni) {
        int n  = n0 + wn * 64 + ni * 16 + lr;
        int h  = n >> 7;
        int d2 = n & 127;
        int d  = d2 & 63;
        bool isk = (d2 >= 64);
        float bvs = bias[n];
#pragma unroll
        for (int mi = 0; mi < 4; ++mi) {
#pragma unroll
            for (int r = 0; r < 4; ++r) {
                int m = m0 + wm * 64 + mi * 16 + kg * 4 + r;
                int bi = m >> 9, lpos = m & 511;
                float v = acc[mi][ni][r] + bvs;
                float partner = __shfl_xor(v, 1);
                float2 cs = tab[lpos * 64 + d];
                float x2 = (d & 1) ? partner : -partner;
                float rot = v * cs.x + x2 * cs.y;
                size_t oidx = (((size_t)bi * HEADS + h) * LSEQ + lpos) * DDIM + d;
                if (isk) kws[oidx] = (__bf16)rot;
                else     qws[oidx] = (__bf16)rot;
            }
        }
    }
}

// ---------------- kernel 3: per-(b,h) QK^T + mask/tril/scale -----------------
__global__ __launch_bounds__(256) void attn_k(
    const __bf16* __restrict__ qws, const __bf16* __restrict__ kws,
    const float* __restrict__ mask, float* __restrict__ out) {

    __shared__ __bf16 Qs[128][72];
    __shared__ __bf16 Ks[128][72];

    const int tid = threadIdx.x;
    const int bh = blockIdx.y;
    const int mtile = blockIdx.x >> 2, ntile = blockIdx.x & 3;
    const int m0 = mtile * 128, n0 = ntile * 128;
    const int wid = tid >> 6, lane = tid & 63;
    const int wm = wid >> 1, wn = wid & 1;
    const int lr = lane & 15, kg = lane >> 4;

    const __bf16* qbase = qws + ((size_t)bh * LSEQ + m0) * DDIM;
    const __bf16* kbase = kws + ((size_t)bh * LSEQ + n0) * DDIM;

    const int r = tid >> 1, c = (tid & 1) * 32;
    {
        uint4 q0 = *(const uint4*)(qbase + r * 64 + c + 0);
        uint4 q1 = *(const uint4*)(qbase + r * 64 + c + 8);
        uint4 q2 = *(const uint4*)(qbase + r * 64 + c + 16);
        uint4 q3 = *(const uint4*)(qbase + r * 64 + c + 24);
        *(uint4*)&Qs[r][c + 0]  = q0;
        *(uint4*)&Qs[r][c + 8]  = q1;
        *(uint4*)&Qs[r][c + 16] = q2;
        *(uint4*)&Qs[r][c + 24] = q3;
        uint4 k0 = *(const uint4*)(kbase + r * 64 + c + 0);
        uint4 k1 = *(const uint4*)(kbase + r * 64 + c + 8);
        uint4 k2 = *(const uint4*)(kbase + r * 64 + c + 16);
        uint4 k3 = *(const uint4*)(kbase + r * 64 + c + 24);
        *(uint4*)&Ks[r][c + 0]  = k0;
        *(uint4*)&Ks[r][c + 8]  = k1;
        *(uint4*)&Ks[r][c + 16] = k2;
        *(uint4*)&Ks[r][c + 24] = k3;
    }
    __syncthreads();

    f32x4 acc[4][4] = {};
#pragma unroll
    for (int ks = 0; ks < 2; ++ks) {
        bf16x8 af[4], bfr[4];
#pragma unroll
        for (int mi = 0; mi < 4; ++mi)
            af[mi] = *(bf16x8*)&Qs[wm * 64 + mi * 16 + lr][ks * 32 + kg * 8];
#pragma unroll
        for (int ni = 0; ni < 4; ++ni)
            bfr[ni] = *(bf16x8*)&Ks[wn * 64 + ni * 16 + lr][ks * 32 + kg * 8];
#pragma unroll
        for (int mi = 0; mi < 4; ++mi)
#pragma unroll
            for (int ni = 0; ni < 4; ++ni)
                acc[mi][ni] = __builtin_amdgcn_mfma_f32_16x16x32_bf16(
                    af[mi], bfr[ni], acc[mi][ni], 0, 0, 0);
    }

    const int b = bh / HEADS;
    float* obase = out + (size_t)bh * LSEQ * LSEQ;
#pragma unroll
    for (int ni = 0; ni < 4; ++ni) {
        int n = n0 + wn * 64 + ni * 16 + lr;
        float padv = mask[b * LSEQ + n];
        float negadd = -(1.0f - padv) * BIG_NEG;
#pragma unroll
        for (int mi = 0; mi < 4; ++mi) {
#pragma unroll
            for (int rr = 0; rr < 4; ++rr) {
                int m = m0 + wm * 64 + mi * 16 + kg * 4 + rr;
                float v = acc[mi][ni][rr];
                v = v * padv + negadd;
                if (m > n) v -= BIG_NEG;
                obase[(size_t)m * LSEQ + n] = v * 0.125f;
            }
        }
    }
}

extern "C" void kernel_launch(void* const* d_in, const int* in_sizes, int n_in,
                              void* d_out, int out_size, void* d_ws, size_t ws_size,
                              hipStream_t stream) {
    const float* X    = (const float*)d_in[0];   // (16,512,768)
    const float* mask = (const float*)d_in[1];   // (16,512)
    const float* W    = (const float*)d_in[2];   // (768,1536)
    const float* bias = (const float*)d_in[3];   // (1536,)
    float* out = (float*)d_out;                  // (16,12,512,512)

    char* ws = (char*)d_ws;
    float2* tab = (float2*)ws;                               // 262144 B
    __bf16* qws = (__bf16*)(ws + 262144);                    // 12582912 B
    __bf16* kws = (__bf16*)(ws + 262144 + 12582912);         // 12582912 B

    rope_tab_k<<<128, 256, 0, stream>>>(tab);
    proj_rope_k<<<dim3(64, 12), 256, 0, stream>>>(X, W, bias, tab, qws, kws);
    attn_k<<<dim3(16, 192), 256, 0, stream>>>(qws, kws, mask, out);
}

// Round 2
// 113.849 us; speedup vs baseline: 1.3094x; 1.3094x over previous
//
#include <hip/hip_runtime.h>
#include <hip/hip_bf16.h>
#include <stdint.h>

typedef __bf16 bf16x8 __attribute__((ext_vector_type(8)));
typedef __bf16 bf16x4 __attribute__((ext_vector_type(4)));
typedef float f32x4 __attribute__((ext_vector_type(4)));

#define HEADS 12
#define DDIM 64
#define LSEQ 512
#define HID 768
#define NOUT 1536
#define BIG_NEG 1000000000000.0f

__device__ __forceinline__ void gl_lds16(const void* g, void* l) {
    __builtin_amdgcn_global_load_lds(
        (const __attribute__((address_space(1))) void*)g,
        (__attribute__((address_space(3))) void*)l, 16, 0, 0);
}

// ---------------- kernel 1: RoPE cos/sin tables (512 x 64 each) --------------
__global__ void rope_tab_k(float* __restrict__ cosT, float* __restrict__ sinT) {
    int idx = blockIdx.x * 256 + threadIdx.x;
    if (idx >= LSEQ * DDIM) return;
    int l = idx >> 6, d = idx & 63;
    int p = d >> 1;
    float inv = powf(10000.0f, (-2.0f * (float)p) / 64.0f);
    float ang = (float)l * inv;
    cosT[idx] = cosf(ang);
    sinT[idx] = sinf(ang);
}

// ---------------- kernel 2: W (768,1536) f32 -> Wt (1536,768) bf16 -----------
__global__ __launch_bounds__(256) void wtrans_k(const float* __restrict__ W,
                                                __bf16* __restrict__ Wt) {
    __shared__ float Ls[32][33];
    int n0 = blockIdx.x * 32, k0 = blockIdx.y * 32;
    int tx = threadIdx.x & 31, ty = threadIdx.x >> 5;   // ty 0..7
#pragma unroll
    for (int rr = 0; rr < 4; ++rr) {
        int k = ty + rr * 8;
        Ls[k][tx] = W[(size_t)(k0 + k) * NOUT + n0 + tx];
    }
    __syncthreads();
#pragma unroll
    for (int rr = 0; rr < 4; ++rr) {
        int n = ty + rr * 8;
        Wt[(size_t)(n0 + n) * HID + k0 + tx] = (__bf16)Ls[tx][n];
    }
}

// ---------------- kernel 3: proj GEMM + bias + RoPE -> bf16 q/k slabs --------
// C^T layout: mfma(A=Wt-frag rows=n, B=X-frag cols=m) -> D[row=n][col=m]
// Lane's 4 acc regs = 4 consecutive n (= consecutive d) -> in-lane RoPE.
__global__ __launch_bounds__(256) void proj_rope_k(
    const float* __restrict__ X, const __bf16* __restrict__ Wt,
    const float* __restrict__ bias, const float* __restrict__ cosT,
    const float* __restrict__ sinT,
    __bf16* __restrict__ qws, __bf16* __restrict__ kws) {

    __shared__ __bf16 As[128 * 64];   // X tile  [m][k], chunk-swizzled
    __shared__ __bf16 Bs[128 * 64];   // Wt tile [n][k], chunk-swizzled

    const int tid = threadIdx.x;
    const int m0 = blockIdx.x * 128, n0 = blockIdx.y * 128;
    const int lane = tid & 63, wid = tid >> 6;
    const int wm = wid >> 1, wn = wid & 1;
    const int lr = lane & 15, kg = lane >> 4;

    const int arow = tid >> 2;            // 0..63 (A staging: 2 passes of 64 rows)
    const int akc  = tid & 3;             // 16-float group within 64-k row
    const int brow = tid >> 3;            // 0..31 (B staging rows per issue)
    const int bch  = tid & 7;             // 16B chunk

    f32x4 acc[4][4] = {};                 // [ai(n)][bi(m)]

    for (int k0 = 0; k0 < HID; k0 += 64) {
        // ---- issue Wt tile via async global->LDS (swizzled source) ----
#pragma unroll
        for (int j = 0; j < 4; ++j) {
            int n = j * 32 + brow;
            int cs = bch ^ (n & 7);
            const __bf16* g = Wt + (size_t)(n0 + n) * HID + k0 + cs * 8;
            gl_lds16(g, (char*)Bs + j * 4096 + tid * 16);
        }
        // ---- A tile: fp32 load -> bf16 -> swizzled ds_write_b128 ----
#pragma unroll
        for (int rr = 0; rr < 2; ++rr) {
            int row = rr * 64 + arow;
            const float* ap = X + (size_t)(m0 + row) * HID + k0 + akc * 16;
            float4 f0 = ((const float4*)ap)[0];
            float4 f1 = ((const float4*)ap)[1];
            float4 f2 = ((const float4*)ap)[2];
            float4 f3 = ((const float4*)ap)[3];
            bf16x8 p0 = {(__bf16)f0.x,(__bf16)f0.y,(__bf16)f0.z,(__bf16)f0.w,
                         (__bf16)f1.x,(__bf16)f1.y,(__bf16)f1.z,(__bf16)f1.w};
            bf16x8 p1 = {(__bf16)f2.x,(__bf16)f2.y,(__bf16)f2.z,(__bf16)f2.w,
                         (__bf16)f3.x,(__bf16)f3.y,(__bf16)f3.z,(__bf16)f3.w};
            int c0 = (akc * 2)     ^ (row & 7);
            int c1 = (akc * 2 + 1) ^ (row & 7);
            *(bf16x8*)((char*)As + row * 128 + c0 * 16) = p0;
            *(bf16x8*)((char*)As + row * 128 + c1 * 16) = p1;
        }
        __syncthreads();
#pragma unroll
        for (int ks = 0; ks < 2; ++ks) {
            bf16x8 af[4], xf[4];
#pragma unroll
            for (int ai = 0; ai < 4; ++ai) {
                int row = wn * 64 + ai * 16 + lr;
                int c = (kg + ks * 4) ^ (row & 7);
                af[ai] = *(bf16x8*)((char*)Bs + row * 128 + c * 16);
            }
#pragma unroll
            for (int bi = 0; bi < 4; ++bi) {
                int row = wm * 64 + bi * 16 + lr;
                int c = (kg + ks * 4) ^ (row & 7);
                xf[bi] = *(bf16x8*)((char*)As + row * 128 + c * 16);
            }
#pragma unroll
            for (int ai = 0; ai < 4; ++ai)
#pragma unroll
                for (int bi = 0; bi < 4; ++bi)
                    acc[ai][bi] = __builtin_amdgcn_mfma_f32_16x16x32_bf16(
                        af[ai], xf[bi], acc[ai][bi], 0, 0, 0);
        }
        __syncthreads();
    }

    // ---- epilogue: bias + in-lane RoPE, 8B vector stores ----
#pragma unroll
    for (int ai = 0; ai < 4; ++ai) {
        int nb = n0 + wn * 64 + ai * 16 + kg * 4;  // 4-aligned
        int h = nb >> 7, d2 = nb & 127;
        int d = d2 & 63;
        __bf16* dst = (d2 >= 64) ? kws : qws;
        float4 b4 = *(const float4*)&bias[nb];
#pragma unroll
        for (int bi = 0; bi < 4; ++bi) {
            int m = m0 + wm * 64 + bi * 16 + lr;
            int bidx = m >> 9, lpos = m & 511;
            float4 c4 = *(const float4*)&cosT[lpos * 64 + d];
            float4 s4 = *(const float4*)&sinT[lpos * 64 + d];
            float v0 = acc[ai][bi][0] + b4.x;
            float v1 = acc[ai][bi][1] + b4.y;
            float v2 = acc[ai][bi][2] + b4.z;
            float v3 = acc[ai][bi][3] + b4.w;
            bf16x4 o;
            o[0] = (__bf16)(v0 * c4.x - v1 * s4.x);
            o[1] = (__bf16)(v1 * c4.y + v0 * s4.y);
            o[2] = (__bf16)(v2 * c4.z - v3 * s4.z);
            o[3] = (__bf16)(v3 * c4.w + v2 * s4.w);
            *(bf16x4*)&dst[(((size_t)bidx * HEADS + h) * LSEQ + lpos) * DDIM + d] = o;
        }
    }
}

// ---------------- kernel 4: per-(b,h) QK^T + mask/tril/scale -----------------
// mfma(A=K-frag rows=n, B=Q-frag cols=m) -> D[n][m]; lane's 4 regs = 4
// consecutive n -> float4 stores of the 201MB output.
__global__ __launch_bounds__(256) void attn_k(
    const __bf16* __restrict__ qws, const __bf16* __restrict__ kws,
    const float* __restrict__ mask, float* __restrict__ out) {

    __shared__ __bf16 Qs[128 * 64];
    __shared__ __bf16 Ks[128 * 64];

    const int tid = threadIdx.x;
    const int bh = blockIdx.y;
    const int mtile = blockIdx.x >> 2, ntile = blockIdx.x & 3;
    const int m0 = mtile * 128, n0 = ntile * 128;
    const int lane = tid & 63, wid = tid >> 6;
    const int wm = wid >> 1, wn = wid & 1;
    const int lr = lane & 15, kg = lane >> 4;

    const __bf16* qbase = qws + ((size_t)bh * LSEQ + m0) * DDIM;
    const __bf16* kbase = kws + ((size_t)bh * LSEQ + n0) * DDIM;

    const int row32 = tid >> 3, ch = tid & 7;
#pragma unroll
    for (int j = 0; j < 4; ++j) {
        int r = j * 32 + row32;
        int cs = ch ^ (r & 7);
        gl_lds16(qbase + (size_t)r * DDIM + cs * 8, (char*)Qs + j * 4096 + tid * 16);
        gl_lds16(kbase + (size_t)r * DDIM + cs * 8, (char*)Ks + j * 4096 + tid * 16);
    }
    __syncthreads();

    f32x4 acc[4][4] = {};                 // [ai(n)][bi(m)]
#pragma unroll
    for (int ks = 0; ks < 2; ++ks) {
        bf16x8 af[4], qf[4];
#pragma unroll
        for (int ai = 0; ai < 4; ++ai) {
            int row = wn * 64 + ai * 16 + lr;
            int c = (kg + ks * 4) ^ (row & 7);
            af[ai] = *(bf16x8*)((char*)Ks + row * 128 + c * 16);
        }
#pragma unroll
        for (int bi = 0; bi < 4; ++bi) {
            int row = wm * 64 + bi * 16 + lr;
            int c = (kg + ks * 4) ^ (row & 7);
            qf[bi] = *(bf16x8*)((char*)Qs + row * 128 + c * 16);
        }
#pragma unroll
        for (int ai = 0; ai < 4; ++ai)
#pragma unroll
            for (int bi = 0; bi < 4; ++bi)
                acc[ai][bi] = __builtin_amdgcn_mfma_f32_16x16x32_bf16(
                    af[ai], qf[bi], acc[ai][bi], 0, 0, 0);
    }

    const int b = bh / HEADS;
    float* obase = out + (size_t)bh * LSEQ * LSEQ;
#pragma unroll
    for (int ai = 0; ai < 4; ++ai) {
        int nb = n0 + wn * 64 + ai * 16 + kg * 4;
        float4 p4 = *(const float4*)&mask[b * LSEQ + nb];
#pragma unroll
        for (int bi = 0; bi < 4; ++bi) {
            int m = m0 + wm * 64 + bi * 16 + lr;
            float4 o;
            o.x = (acc[ai][bi][0] * p4.x - (1.0f - p4.x) * BIG_NEG
                   - ((m > nb + 0) ? BIG_NEG : 0.0f)) * 0.125f;
            o.y = (acc[ai][bi][1] * p4.y - (1.0f - p4.y) * BIG_NEG
                   - ((m > nb + 1) ? BIG_NEG : 0.0f)) * 0.125f;
            o.z = (acc[ai][bi][2] * p4.z - (1.0f - p4.z) * BIG_NEG
                   - ((m > nb + 2) ? BIG_NEG : 0.0f)) * 0.125f;
            o.w = (acc[ai][bi][3] * p4.w - (1.0f - p4.w) * BIG_NEG
                   - ((m > nb + 3) ? BIG_NEG : 0.0f)) * 0.125f;
            *(float4*)&obase[(size_t)m * LSEQ + nb] = o;
        }
    }
}

extern "C" void kernel_launch(void* const* d_in, const int* in_sizes, int n_in,
                              void* d_out, int out_size, void* d_ws, size_t ws_size,
                              hipStream_t stream) {
    const float* X    = (const float*)d_in[0];   // (16,512,768)
    const float* mask = (const float*)d_in[1];   // (16,512)
    const float* W    = (const float*)d_in[2];   // (768,1536)
    const float* bias = (const float*)d_in[3];   // (1536,)
    float* out = (float*)d_out;                  // (16,12,512,512)

    char* ws = (char*)d_ws;
    float*  cosT = (float*)ws;                          // 131072 B
    float*  sinT = (float*)(ws + 131072);               // 131072 B
    __bf16* Wt   = (__bf16*)(ws + 262144);              // 2359296 B
    __bf16* qws  = (__bf16*)(ws + 2621440);             // 12582912 B
    __bf16* kws  = (__bf16*)(ws + 2621440 + 12582912);  // 12582912 B

    rope_tab_k<<<128, 256, 0, stream>>>(cosT, sinT);
    wtrans_k<<<dim3(48, 24), 256, 0, stream>>>(W, Wt);
    proj_rope_k<<<dim3(64, 12), 256, 0, stream>>>(X, Wt, bias, cosT, sinT, qws, kws);
    attn_k<<<dim3(16, 192), 256, 0, stream>>>(qws, kws, mask, out);
}

// Round 3
// 105.788 us; speedup vs baseline: 1.4092x; 1.0762x over previous
//
#include <hip/hip_runtime.h>
#include <hip/hip_bf16.h>
#include <stdint.h>

typedef __bf16 bf16x8 __attribute__((ext_vector_type(8)));
typedef __bf16 bf16x4 __attribute__((ext_vector_type(4)));
typedef float f32x4 __attribute__((ext_vector_type(4)));

#define HEADS 12
#define DDIM 64
#define LSEQ 512
#define HID 768
#define NOUT 1536
#define BIG_NEG 1000000000000.0f

__device__ __forceinline__ void gl_lds16(const void* g, void* l) {
    __builtin_amdgcn_global_load_lds(
        (const __attribute__((address_space(1))) void*)g,
        (__attribute__((address_space(3))) void*)l, 16, 0, 0);
}

// ---- kernel 1 (fused prep): X->bf16, W->Wt bf16 transpose, RoPE tables ------
// blocks [0,3072): X conversion (8 f32 -> 8 bf16 per thread)
// blocks [3072,4224): W transpose tile 32x32
// blocks [4224,4352): cos/sin tables
__global__ __launch_bounds__(256) void prep_k(
    const float* __restrict__ X, const float* __restrict__ W,
    __bf16* __restrict__ Xb, __bf16* __restrict__ Wt,
    float* __restrict__ cosT, float* __restrict__ sinT) {

    int blk = blockIdx.x;
    if (blk < 3072) {
        size_t idx = ((size_t)blk * 256 + threadIdx.x) * 8;
        float4 f0 = *(const float4*)(X + idx);
        float4 f1 = *(const float4*)(X + idx + 4);
        bf16x8 p = {(__bf16)f0.x,(__bf16)f0.y,(__bf16)f0.z,(__bf16)f0.w,
                    (__bf16)f1.x,(__bf16)f1.y,(__bf16)f1.z,(__bf16)f1.w};
        *(bf16x8*)(Xb + idx) = p;
    } else if (blk < 4224) {
        __shared__ float Ls[32][33];
        int b2 = blk - 3072;
        int n0 = (b2 % 48) * 32, k0 = (b2 / 48) * 32;
        int tx = threadIdx.x & 31, ty = threadIdx.x >> 5;
#pragma unroll
        for (int rr = 0; rr < 4; ++rr) {
            int k = ty + rr * 8;
            Ls[k][tx] = W[(size_t)(k0 + k) * NOUT + n0 + tx];
        }
        __syncthreads();
#pragma unroll
        for (int rr = 0; rr < 4; ++rr) {
            int n = ty + rr * 8;
            Wt[(size_t)(n0 + n) * HID + k0 + tx] = (__bf16)Ls[tx][n];
        }
    } else {
        int idx = (blk - 4224) * 256 + threadIdx.x;
        int l = idx >> 6, d = idx & 63;
        int p = d >> 1;
        float inv = powf(10000.0f, (-2.0f * (float)p) / 64.0f);
        float ang = (float)l * inv;
        cosT[idx] = cosf(ang);
        sinT[idx] = sinf(ang);
    }
}

// ---------------- kernel 2: proj GEMM + bias + RoPE -> bf16 q/k slabs --------
// Both operands staged via global_load_lds (16B), pre-swizzled source chunks.
// mfma(A=Wt-frag rows=n, B=Xb-frag cols=m) -> D[row=n][col=m];
// lane's 4 acc regs = 4 consecutive n (= consecutive d) -> in-lane RoPE.
__global__ __launch_bounds__(256) void proj_rope_k(
    const __bf16* __restrict__ Xb, const __bf16* __restrict__ Wt,
    const float* __restrict__ bias, const float* __restrict__ cosT,
    const float* __restrict__ sinT,
    __bf16* __restrict__ qws, __bf16* __restrict__ kws) {

    __shared__ __bf16 As[128 * 64];   // Xb tile [m][64k], chunk-swizzled
    __shared__ __bf16 Bs[128 * 64];   // Wt tile [n][64k], chunk-swizzled

    const int tid = threadIdx.x;
    const int m0 = blockIdx.x * 128, n0 = blockIdx.y * 128;
    const int lane = tid & 63, wid = tid >> 6;
    const int wm = wid >> 1, wn = wid & 1;
    const int lr = lane & 15, kg = lane >> 4;

    const int srow = tid >> 3;            // 0..31 staging row per issue
    const int sch  = tid & 7;             // 16B chunk 0..7

    f32x4 acc[4][4] = {};                 // [ai(n)][bi(m)]

    for (int k0 = 0; k0 < HID; k0 += 64) {
#pragma unroll
        for (int j = 0; j < 4; ++j) {
            int r = j * 32 + srow;
            int cs = sch ^ (r & 7);
            gl_lds16(Wt + (size_t)(n0 + r) * HID + k0 + cs * 8,
                     (char*)Bs + j * 4096 + tid * 16);
            gl_lds16(Xb + (size_t)(m0 + r) * HID + k0 + cs * 8,
                     (char*)As + j * 4096 + tid * 16);
        }
        __syncthreads();
#pragma unroll
        for (int ks = 0; ks < 2; ++ks) {
            bf16x8 af[4], xf[4];
#pragma unroll
            for (int ai = 0; ai < 4; ++ai) {
                int row = wn * 64 + ai * 16 + lr;
                int c = (kg + ks * 4) ^ (row & 7);
                af[ai] = *(bf16x8*)((char*)Bs + row * 128 + c * 16);
            }
#pragma unroll
            for (int bi = 0; bi < 4; ++bi) {
                int row = wm * 64 + bi * 16 + lr;
                int c = (kg + ks * 4) ^ (row & 7);
                xf[bi] = *(bf16x8*)((char*)As + row * 128 + c * 16);
            }
#pragma unroll
            for (int ai = 0; ai < 4; ++ai)
#pragma unroll
                for (int bi = 0; bi < 4; ++bi)
                    acc[ai][bi] = __builtin_amdgcn_mfma_f32_16x16x32_bf16(
                        af[ai], xf[bi], acc[ai][bi], 0, 0, 0);
        }
        __syncthreads();
    }

    // ---- epilogue: bias + in-lane RoPE, 8B vector stores ----
#pragma unroll
    for (int ai = 0; ai < 4; ++ai) {
        int nb = n0 + wn * 64 + ai * 16 + kg * 4;  // 4-aligned
        int h = nb >> 7, d2 = nb & 127;
        int d = d2 & 63;
        __bf16* dst = (d2 >= 64) ? kws : qws;
        float4 b4 = *(const float4*)&bias[nb];
#pragma unroll
        for (int bi = 0; bi < 4; ++bi) {
            int m = m0 + wm * 64 + bi * 16 + lr;
            int bidx = m >> 9, lpos = m & 511;
            float4 c4 = *(const float4*)&cosT[lpos * 64 + d];
            float4 s4 = *(const float4*)&sinT[lpos * 64 + d];
            float v0 = acc[ai][bi][0] + b4.x;
            float v1 = acc[ai][bi][1] + b4.y;
            float v2 = acc[ai][bi][2] + b4.z;
            float v3 = acc[ai][bi][3] + b4.w;
            bf16x4 o;
            o[0] = (__bf16)(v0 * c4.x - v1 * s4.x);
            o[1] = (__bf16)(v1 * c4.y + v0 * s4.y);
            o[2] = (__bf16)(v2 * c4.z - v3 * s4.z);
            o[3] = (__bf16)(v3 * c4.w + v2 * s4.w);
            *(bf16x4*)&dst[(((size_t)bidx * HEADS + h) * LSEQ + lpos) * DDIM + d] = o;
        }
    }
}

// ---------------- kernel 3: per-(b,h) QK^T + mask/tril/scale -----------------
// mfma(A=K-frag rows=n, B=Q-frag cols=m) -> D[n][m]; lane's 4 regs = 4
// consecutive n -> nontemporal float4 stores of the 201MB output.
__global__ __launch_bounds__(256) void attn_k(
    const __bf16* __restrict__ qws, const __bf16* __restrict__ kws,
    const float* __restrict__ mask, float* __restrict__ out) {

    __shared__ __bf16 Qs[128 * 64];
    __shared__ __bf16 Ks[128 * 64];

    const int tid = threadIdx.x;
    const int bh = blockIdx.y;
    const int mtile = blockIdx.x >> 2, ntile = blockIdx.x & 3;
    const int m0 = mtile * 128, n0 = ntile * 128;
    const int lane = tid & 63, wid = tid >> 6;
    const int wm = wid >> 1, wn = wid & 1;
    const int lr = lane & 15, kg = lane >> 4;

    const __bf16* qbase = qws + ((size_t)bh * LSEQ + m0) * DDIM;
    const __bf16* kbase = kws + ((size_t)bh * LSEQ + n0) * DDIM;

    const int row32 = tid >> 3, ch = tid & 7;
#pragma unroll
    for (int j = 0; j < 4; ++j) {
        int r = j * 32 + row32;
        int cs = ch ^ (r & 7);
        gl_lds16(qbase + (size_t)r * DDIM + cs * 8, (char*)Qs + j * 4096 + tid * 16);
        gl_lds16(kbase + (size_t)r * DDIM + cs * 8, (char*)Ks + j * 4096 + tid * 16);
    }
    __syncthreads();

    f32x4 acc[4][4] = {};                 // [ai(n)][bi(m)]
#pragma unroll
    for (int ks = 0; ks < 2; ++ks) {
        bf16x8 af[4], qf[4];
#pragma unroll
        for (int ai = 0; ai < 4; ++ai) {
            int row = wn * 64 + ai * 16 + lr;
            int c = (kg + ks * 4) ^ (row & 7);
            af[ai] = *(bf16x8*)((char*)Ks + row * 128 + c * 16);
        }
#pragma unroll
        for (int bi = 0; bi < 4; ++bi) {
            int row = wm * 64 + bi * 16 + lr;
            int c = (kg + ks * 4) ^ (row & 7);
            qf[bi] = *(bf16x8*)((char*)Qs + row * 128 + c * 16);
        }
#pragma unroll
        for (int ai = 0; ai < 4; ++ai)
#pragma unroll
            for (int bi = 0; bi < 4; ++bi)
                acc[ai][bi] = __builtin_amdgcn_mfma_f32_16x16x32_bf16(
                    af[ai], qf[bi], acc[ai][bi], 0, 0, 0);
    }

    const int b = bh / HEADS;
    float* obase = out + (size_t)bh * LSEQ * LSEQ;
#pragma unroll
    for (int ai = 0; ai < 4; ++ai) {
        int nb = n0 + wn * 64 + ai * 16 + kg * 4;
        float4 p4 = *(const float4*)&mask[b * LSEQ + nb];
#pragma unroll
        for (int bi = 0; bi < 4; ++bi) {
            int m = m0 + wm * 64 + bi * 16 + lr;
            f32x4 o;
            o[0] = (acc[ai][bi][0] * p4.x - (1.0f - p4.x) * BIG_NEG
                   - ((m > nb + 0) ? BIG_NEG : 0.0f)) * 0.125f;
            o[1] = (acc[ai][bi][1] * p4.y - (1.0f - p4.y) * BIG_NEG
                   - ((m > nb + 1) ? BIG_NEG : 0.0f)) * 0.125f;
            o[2] = (acc[ai][bi][2] * p4.z - (1.0f - p4.z) * BIG_NEG
                   - ((m > nb + 2) ? BIG_NEG : 0.0f)) * 0.125f;
            o[3] = (acc[ai][bi][3] * p4.w - (1.0f - p4.w) * BIG_NEG
                   - ((m > nb + 3) ? BIG_NEG : 0.0f)) * 0.125f;
            __builtin_nontemporal_store(o, (f32x4*)&obase[(size_t)m * LSEQ + nb]);
        }
    }
}

extern "C" void kernel_launch(void* const* d_in, const int* in_sizes, int n_in,
                              void* d_out, int out_size, void* d_ws, size_t ws_size,
                              hipStream_t stream) {
    const float* X    = (const float*)d_in[0];   // (16,512,768)
    const float* mask = (const float*)d_in[1];   // (16,512)
    const float* W    = (const float*)d_in[2];   // (768,1536)
    const float* bias = (const float*)d_in[3];   // (1536,)
    float* out = (float*)d_out;                  // (16,12,512,512)

    char* ws = (char*)d_ws;
    float*  cosT = (float*)ws;                            // 131072 B
    float*  sinT = (float*)(ws + 131072);                 // 131072 B
    __bf16* Wt   = (__bf16*)(ws + 262144);                // 2359296 B
    __bf16* Xb   = (__bf16*)(ws + 2621440);               // 12582912 B
    __bf16* qws  = (__bf16*)(ws + 2621440 + 12582912);    // 12582912 B
    __bf16* kws  = (__bf16*)(ws + 2621440 + 2*12582912);  // 12582912 B

    prep_k<<<4352, 256, 0, stream>>>(X, W, Xb, Wt, cosT, sinT);
    proj_rope_k<<<dim3(64, 12), 256, 0, stream>>>(Xb, Wt, bias, cosT, sinT, qws, kws);
    attn_k<<<dim3(16, 192), 256, 0, stream>>>(qws, kws, mask, out);
}

// Round 4
// 96.585 us; speedup vs baseline: 1.5435x; 1.0953x over previous
//
#include <hip/hip_runtime.h>
#include <hip/hip_bf16.h>
#include <stdint.h>

typedef __bf16 bf16x8 __attribute__((ext_vector_type(8)));
typedef __bf16 bf16x4 __attribute__((ext_vector_type(4)));
typedef float f32x4 __attribute__((ext_vector_type(4)));

#define HEADS 12
#define DDIM 64
#define LSEQ 512
#define HID 768
#define NOUT 1536
#define BIG_NEG 1000000000000.0f

__device__ __forceinline__ void gl_lds16(const void* g, void* l) {
    __builtin_amdgcn_global_load_lds(
        (const __attribute__((address_space(1))) void*)g,
        (__attribute__((address_space(3))) void*)l, 16, 0, 0);
}

// ---- kernel 1 (fused prep): X->bf16, W->Wt bf16 transpose, RoPE tables ------
__global__ __launch_bounds__(256) void prep_k(
    const float* __restrict__ X, const float* __restrict__ W,
    __bf16* __restrict__ Xb, __bf16* __restrict__ Wt,
    float* __restrict__ cosT, float* __restrict__ sinT) {

    int blk = blockIdx.x;
    if (blk < 3072) {
        size_t idx = ((size_t)blk * 256 + threadIdx.x) * 8;
        float4 f0 = *(const float4*)(X + idx);
        float4 f1 = *(const float4*)(X + idx + 4);
        bf16x8 p = {(__bf16)f0.x,(__bf16)f0.y,(__bf16)f0.z,(__bf16)f0.w,
                    (__bf16)f1.x,(__bf16)f1.y,(__bf16)f1.z,(__bf16)f1.w};
        *(bf16x8*)(Xb + idx) = p;
    } else if (blk < 4224) {
        __shared__ float Ls[32][33];
        int b2 = blk - 3072;
        int n0 = (b2 % 48) * 32, k0 = (b2 / 48) * 32;
        int tx = threadIdx.x & 31, ty = threadIdx.x >> 5;
#pragma unroll
        for (int rr = 0; rr < 4; ++rr) {
            int k = ty + rr * 8;
            Ls[k][tx] = W[(size_t)(k0 + k) * NOUT + n0 + tx];
        }
        __syncthreads();
#pragma unroll
        for (int rr = 0; rr < 4; ++rr) {
            int n = ty + rr * 8;
            Wt[(size_t)(n0 + n) * HID + k0 + tx] = (__bf16)Ls[tx][n];
        }
    } else {
        int idx = (blk - 4224) * 256 + threadIdx.x;
        int l = idx >> 6, d = idx & 63;
        int p = d >> 1;
        float inv = powf(10000.0f, (-2.0f * (float)p) / 64.0f);
        float ang = (float)l * inv;
        cosT[idx] = cosf(ang);
        sinT[idx] = sinf(ang);
    }
}

// ---------------- kernel 2: proj GEMM + bias + RoPE -> bf16 q/k slabs --------
__global__ __launch_bounds__(256) void proj_rope_k(
    const __bf16* __restrict__ Xb, const __bf16* __restrict__ Wt,
    const float* __restrict__ bias, const float* __restrict__ cosT,
    const float* __restrict__ sinT,
    __bf16* __restrict__ qws, __bf16* __restrict__ kws) {

    __shared__ __bf16 As[128 * 64];   // Xb tile [m][64k], chunk-swizzled
    __shared__ __bf16 Bs[128 * 64];   // Wt tile [n][64k], chunk-swizzled

    const int tid = threadIdx.x;
    const int m0 = blockIdx.x * 128, n0 = blockIdx.y * 128;
    const int lane = tid & 63, wid = tid >> 6;
    const int wm = wid >> 1, wn = wid & 1;
    const int lr = lane & 15, kg = lane >> 4;

    const int srow = tid >> 3;            // 0..31 staging row per issue
    const int sch  = tid & 7;             // 16B chunk 0..7

    f32x4 acc[4][4] = {};                 // [ai(n)][bi(m)]

    for (int k0 = 0; k0 < HID; k0 += 64) {
#pragma unroll
        for (int j = 0; j < 4; ++j) {
            int r = j * 32 + srow;
            int cs = sch ^ (r & 7);
            gl_lds16(Wt + (size_t)(n0 + r) * HID + k0 + cs * 8,
                     (char*)Bs + j * 4096 + tid * 16);
            gl_lds16(Xb + (size_t)(m0 + r) * HID + k0 + cs * 8,
                     (char*)As + j * 4096 + tid * 16);
        }
        __syncthreads();
#pragma unroll
        for (int ks = 0; ks < 2; ++ks) {
            bf16x8 af[4], xf[4];
#pragma unroll
            for (int ai = 0; ai < 4; ++ai) {
                int row = wn * 64 + ai * 16 + lr;
                int c = (kg + ks * 4) ^ (row & 7);
                af[ai] = *(bf16x8*)((char*)Bs + row * 128 + c * 16);
            }
#pragma unroll
            for (int bi = 0; bi < 4; ++bi) {
                int row = wm * 64 + bi * 16 + lr;
                int c = (kg + ks * 4) ^ (row & 7);
                xf[bi] = *(bf16x8*)((char*)As + row * 128 + c * 16);
            }
#pragma unroll
            for (int ai = 0; ai < 4; ++ai)
#pragma unroll
                for (int bi = 0; bi < 4; ++bi)
                    acc[ai][bi] = __builtin_amdgcn_mfma_f32_16x16x32_bf16(
                        af[ai], xf[bi], acc[ai][bi], 0, 0, 0);
        }
        __syncthreads();
    }

    // ---- epilogue: bias + in-lane RoPE, 8B vector stores ----
#pragma unroll
    for (int ai = 0; ai < 4; ++ai) {
        int nb = n0 + wn * 64 + ai * 16 + kg * 4;  // 4-aligned
        int h = nb >> 7, d2 = nb & 127;
        int d = d2 & 63;
        __bf16* dst = (d2 >= 64) ? kws : qws;
        float4 b4 = *(const float4*)&bias[nb];
#pragma unroll
        for (int bi = 0; bi < 4; ++bi) {
            int m = m0 + wm * 64 + bi * 16 + lr;
            int bidx = m >> 9, lpos = m & 511;
            float4 c4 = *(const float4*)&cosT[lpos * 64 + d];
            float4 s4 = *(const float4*)&sinT[lpos * 64 + d];
            float v0 = acc[ai][bi][0] + b4.x;
            float v1 = acc[ai][bi][1] + b4.y;
            float v2 = acc[ai][bi][2] + b4.z;
            float v3 = acc[ai][bi][3] + b4.w;
            bf16x4 o;
            o[0] = (__bf16)(v0 * c4.x - v1 * s4.x);
            o[1] = (__bf16)(v1 * c4.y + v0 * s4.y);
            o[2] = (__bf16)(v2 * c4.z - v3 * s4.z);
            o[3] = (__bf16)(v3 * c4.w + v2 * s4.w);
            *(bf16x4*)&dst[(((size_t)bidx * HEADS + h) * LSEQ + lpos) * DDIM + d] = o;
        }
    }
}

// ---------------- kernel 3: per-(b,h) QK^T + mask/tril/scale -----------------
// mfma(A=K-frag rows=n, B=Q-frag cols=m) -> D[n][m].
// Epilogue: 4 rounds of 32-row LDS staging (reusing Qs/Ks space) ->
// fully-coalesced float4 row stores (1KB/wave-instruction), fused mask/tril.
__global__ __launch_bounds__(256) void attn_k(
    const __bf16* __restrict__ qws, const __bf16* __restrict__ kws,
    const float* __restrict__ mask, float* __restrict__ out) {

    __shared__ __align__(16) char smem[32768];
    __bf16* Qs = (__bf16*)smem;                 // 16 KB
    __bf16* Ks = (__bf16*)(smem + 16384);       // 16 KB
    float*  Es = (float*)smem;                  // epilogue: 32 x 132 f32 (16.9 KB)

    const int tid = threadIdx.x;
    const int bh = blockIdx.y;
    const int mtile = blockIdx.x >> 2, ntile = blockIdx.x & 3;
    const int m0 = mtile * 128, n0 = ntile * 128;
    const int lane = tid & 63, wid = tid >> 6;
    const int wm = wid >> 1, wn = wid & 1;
    const int lr = lane & 15, kg = lane >> 4;

    const __bf16* qbase = qws + ((size_t)bh * LSEQ + m0) * DDIM;
    const __bf16* kbase = kws + ((size_t)bh * LSEQ + n0) * DDIM;

    const int row32 = tid >> 3, ch = tid & 7;
#pragma unroll
    for (int j = 0; j < 4; ++j) {
        int r = j * 32 + row32;
        int cs = ch ^ (r & 7);
        gl_lds16(qbase + (size_t)r * DDIM + cs * 8, (char*)Qs + j * 4096 + tid * 16);
        gl_lds16(kbase + (size_t)r * DDIM + cs * 8, (char*)Ks + j * 4096 + tid * 16);
    }
    __syncthreads();

    f32x4 acc[4][4] = {};                 // [ai(n)][bi(m)]
#pragma unroll
    for (int ks = 0; ks < 2; ++ks) {
        bf16x8 af[4], qf[4];
#pragma unroll
        for (int ai = 0; ai < 4; ++ai) {
            int row = wn * 64 + ai * 16 + lr;
            int c = (kg + ks * 4) ^ (row & 7);
            af[ai] = *(bf16x8*)((char*)Ks + row * 128 + c * 16);
        }
#pragma unroll
        for (int bi = 0; bi < 4; ++bi) {
            int row = wm * 64 + bi * 16 + lr;
            int c = (kg + ks * 4) ^ (row & 7);
            qf[bi] = *(bf16x8*)((char*)Qs + row * 128 + c * 16);
        }
#pragma unroll
        for (int ai = 0; ai < 4; ++ai)
#pragma unroll
            for (int bi = 0; bi < 4; ++bi)
                acc[ai][bi] = __builtin_amdgcn_mfma_f32_16x16x32_bf16(
                    af[ai], qf[bi], acc[ai][bi], 0, 0, 0);
    }

    // ---- epilogue: LDS transpose -> coalesced row stores ----
    const int b = bh / HEADS;
    const int colb = (tid & 31) * 4;            // 0..124
    const int rrow = tid >> 5;                  // 0..7
    const float4 p4 = *(const float4*)&mask[b * LSEQ + n0 + colb];
    float* obase = out + (size_t)bh * LSEQ * LSEQ;

#pragma unroll
    for (int p = 0; p < 4; ++p) {
        __syncthreads();   // Es (and Qs/Ks at p=0) free of readers
        if (wm == (p >> 1)) {
            const int bi0 = (p & 1) * 2;
#pragma unroll
            for (int bb = 0; bb < 2; ++bb) {
                int bi = bi0 + bb;
                int row = bb * 16 + lr;                    // 0..31
#pragma unroll
                for (int ai = 0; ai < 4; ++ai) {
                    int n = wn * 64 + ai * 16 + kg * 4;
                    *(f32x4*)&Es[row * 132 + n] = acc[ai][bi];
                }
            }
        }
        __syncthreads();
#pragma unroll
        for (int j = 0; j < 4; ++j) {
            int rloc = rrow + j * 8;                       // 0..31
            int m = m0 + p * 32 + rloc;
            f32x4 v = *(f32x4*)&Es[rloc * 132 + colb];
            int n = n0 + colb;
            f32x4 o;
            o[0] = (v[0] * p4.x - (1.0f - p4.x) * BIG_NEG
                    - ((m > n + 0) ? BIG_NEG : 0.0f)) * 0.125f;
            o[1] = (v[1] * p4.y - (1.0f - p4.y) * BIG_NEG
                    - ((m > n + 1) ? BIG_NEG : 0.0f)) * 0.125f;
            o[2] = (v[2] * p4.z - (1.0f - p4.z) * BIG_NEG
                    - ((m > n + 2) ? BIG_NEG : 0.0f)) * 0.125f;
            o[3] = (v[3] * p4.w - (1.0f - p4.w) * BIG_NEG
                    - ((m > n + 3) ? BIG_NEG : 0.0f)) * 0.125f;
            __builtin_nontemporal_store(o, (f32x4*)&obase[(size_t)m * LSEQ + n]);
        }
    }
}

extern "C" void kernel_launch(void* const* d_in, const int* in_sizes, int n_in,
                              void* d_out, int out_size, void* d_ws, size_t ws_size,
                              hipStream_t stream) {
    const float* X    = (const float*)d_in[0];   // (16,512,768)
    const float* mask = (const float*)d_in[1];   // (16,512)
    const float* W    = (const float*)d_in[2];   // (768,1536)
    const float* bias = (const float*)d_in[3];   // (1536,)
    float* out = (float*)d_out;                  // (16,12,512,512)

    char* ws = (char*)d_ws;
    float*  cosT = (float*)ws;                            // 131072 B
    float*  sinT = (float*)(ws + 131072);                 // 131072 B
    __bf16* Wt   = (__bf16*)(ws + 262144);                // 2359296 B
    __bf16* Xb   = (__bf16*)(ws + 2621440);               // 12582912 B
    __bf16* qws  = (__bf16*)(ws + 2621440 + 12582912);    // 12582912 B
    __bf16* kws  = (__bf16*)(ws + 2621440 + 2*12582912);  // 12582912 B

    prep_k<<<4352, 256, 0, stream>>>(X, W, Xb, Wt, cosT, sinT);
    proj_rope_k<<<dim3(64, 12), 256, 0, stream>>>(Xb, Wt, bias, cosT, sinT, qws, kws);
    attn_k<<<dim3(16, 192), 256, 0, stream>>>(qws, kws, mask, out);
}

// Round 5
// 94.050 us; speedup vs baseline: 1.5851x; 1.0270x over previous
//
#include <hip/hip_runtime.h>
#include <hip/hip_bf16.h>
#include <stdint.h>

typedef __bf16 bf16x8 __attribute__((ext_vector_type(8)));
typedef __bf16 bf16x4 __attribute__((ext_vector_type(4)));
typedef float f32x4 __attribute__((ext_vector_type(4)));

#define HEADS 12
#define DDIM 64
#define LSEQ 512
#define HID 768
#define NOUT 1536
#define BIG_NEG 1000000000000.0f

__device__ __forceinline__ void gl_lds16(const void* g, void* l) {
    __builtin_amdgcn_global_load_lds(
        (const __attribute__((address_space(1))) void*)g,
        (__attribute__((address_space(3))) void*)l, 16, 0, 0);
}

// barrier that orders LDS only — does NOT drain vmcnt (NT stores stay in flight)
__device__ __forceinline__ void ldsbar() {
    asm volatile("s_waitcnt lgkmcnt(0)" ::: "memory");
    __builtin_amdgcn_s_barrier();
}

// ---- kernel 1 (fused prep): X->bf16, W->Wt bf16 transpose, RoPE tables ------
__global__ __launch_bounds__(256) void prep_k(
    const float* __restrict__ X, const float* __restrict__ W,
    __bf16* __restrict__ Xb, __bf16* __restrict__ Wt,
    float* __restrict__ cosT, float* __restrict__ sinT) {

    int blk = blockIdx.x;
    if (blk < 3072) {
        size_t idx = ((size_t)blk * 256 + threadIdx.x) * 8;
        float4 f0 = *(const float4*)(X + idx);
        float4 f1 = *(const float4*)(X + idx + 4);
        bf16x8 p = {(__bf16)f0.x,(__bf16)f0.y,(__bf16)f0.z,(__bf16)f0.w,
                    (__bf16)f1.x,(__bf16)f1.y,(__bf16)f1.z,(__bf16)f1.w};
        *(bf16x8*)(Xb + idx) = p;
    } else if (blk < 4224) {
        __shared__ float Ls[32][33];
        int b2 = blk - 3072;
        int n0 = (b2 % 48) * 32, k0 = (b2 / 48) * 32;
        int tx = threadIdx.x & 31, ty = threadIdx.x >> 5;
#pragma unroll
        for (int rr = 0; rr < 4; ++rr) {
            int k = ty + rr * 8;
            Ls[k][tx] = W[(size_t)(k0 + k) * NOUT + n0 + tx];
        }
        __syncthreads();
#pragma unroll
        for (int rr = 0; rr < 4; ++rr) {
            int n = ty + rr * 8;
            Wt[(size_t)(n0 + n) * HID + k0 + tx] = (__bf16)Ls[tx][n];
        }
    } else {
        int idx = (blk - 4224) * 256 + threadIdx.x;
        int l = idx >> 6, d = idx & 63;
        int p = d >> 1;
        float inv = powf(10000.0f, (-2.0f * (float)p) / 64.0f);
        float ang = (float)l * inv;
        cosT[idx] = cosf(ang);
        sinT[idx] = sinf(ang);
    }
}

// ---------------- kernel 2: proj GEMM + bias + RoPE -> bf16 q/k slabs --------
__global__ __launch_bounds__(256) void proj_rope_k(
    const __bf16* __restrict__ Xb, const __bf16* __restrict__ Wt,
    const float* __restrict__ bias, const float* __restrict__ cosT,
    const float* __restrict__ sinT,
    __bf16* __restrict__ qws, __bf16* __restrict__ kws) {

    __shared__ __bf16 As[128 * 64];   // Xb tile [m][64k], chunk-swizzled
    __shared__ __bf16 Bs[128 * 64];   // Wt tile [n][64k], chunk-swizzled

    const int tid = threadIdx.x;
    const int m0 = blockIdx.x * 128, n0 = blockIdx.y * 128;
    const int lane = tid & 63, wid = tid >> 6;
    const int wm = wid >> 1, wn = wid & 1;
    const int lr = lane & 15, kg = lane >> 4;

    const int srow = tid >> 3;            // 0..31 staging row per issue
    const int sch  = tid & 7;             // 16B chunk 0..7

    f32x4 acc[4][4] = {};                 // [ai(n)][bi(m)]

    for (int k0 = 0; k0 < HID; k0 += 64) {
#pragma unroll
        for (int j = 0; j < 4; ++j) {
            int r = j * 32 + srow;
            int cs = sch ^ (r & 7);
            gl_lds16(Wt + (size_t)(n0 + r) * HID + k0 + cs * 8,
                     (char*)Bs + j * 4096 + tid * 16);
            gl_lds16(Xb + (size_t)(m0 + r) * HID + k0 + cs * 8,
                     (char*)As + j * 4096 + tid * 16);
        }
        __syncthreads();
#pragma unroll
        for (int ks = 0; ks < 2; ++ks) {
            bf16x8 af[4], xf[4];
#pragma unroll
            for (int ai = 0; ai < 4; ++ai) {
                int row = wn * 64 + ai * 16 + lr;
                int c = (kg + ks * 4) ^ (row & 7);
                af[ai] = *(bf16x8*)((char*)Bs + row * 128 + c * 16);
            }
#pragma unroll
            for (int bi = 0; bi < 4; ++bi) {
                int row = wm * 64 + bi * 16 + lr;
                int c = (kg + ks * 4) ^ (row & 7);
                xf[bi] = *(bf16x8*)((char*)As + row * 128 + c * 16);
            }
#pragma unroll
            for (int ai = 0; ai < 4; ++ai)
#pragma unroll
                for (int bi = 0; bi < 4; ++bi)
                    acc[ai][bi] = __builtin_amdgcn_mfma_f32_16x16x32_bf16(
                        af[ai], xf[bi], acc[ai][bi], 0, 0, 0);
        }
        __syncthreads();
    }

    // ---- epilogue: bias + in-lane RoPE, 8B vector stores ----
#pragma unroll
    for (int ai = 0; ai < 4; ++ai) {
        int nb = n0 + wn * 64 + ai * 16 + kg * 4;  // 4-aligned
        int h = nb >> 7, d2 = nb & 127;
        int d = d2 & 63;
        __bf16* dst = (d2 >= 64) ? kws : qws;
        float4 b4 = *(const float4*)&bias[nb];
#pragma unroll
        for (int bi = 0; bi < 4; ++bi) {
            int m = m0 + wm * 64 + bi * 16 + lr;
            int bidx = m >> 9, lpos = m & 511;
            float4 c4 = *(const float4*)&cosT[lpos * 64 + d];
            float4 s4 = *(const float4*)&sinT[lpos * 64 + d];
            float v0 = acc[ai][bi][0] + b4.x;
            float v1 = acc[ai][bi][1] + b4.y;
            float v2 = acc[ai][bi][2] + b4.z;
            float v3 = acc[ai][bi][3] + b4.w;
            bf16x4 o;
            o[0] = (__bf16)(v0 * c4.x - v1 * s4.x);
            o[1] = (__bf16)(v1 * c4.y + v0 * s4.y);
            o[2] = (__bf16)(v2 * c4.z - v3 * s4.z);
            o[3] = (__bf16)(v3 * c4.w + v2 * s4.w);
            *(bf16x4*)&dst[(((size_t)bidx * HEADS + h) * LSEQ + lpos) * DDIM + d] = o;
        }
    }
}

// ---------------- kernel 3: QK^T + mask/tril/scale, 128m x 512n per block ----
// Q staged once; K prefetched one tile ahead; epilogue uses raw lgkm-only
// barriers so NT stores never stall a round; counted vmcnt(16) at phase edge.
__global__ __launch_bounds__(256) void attn_k(
    const __bf16* __restrict__ qws, const __bf16* __restrict__ kws,
    const float* __restrict__ mask, float* __restrict__ out) {

    __shared__ __align__(16) char smem[49664];
    __bf16* Qs = (__bf16*)smem;                 // 16 KB
    __bf16* Ks = (__bf16*)(smem + 16384);       // 16 KB
    float*  Es = (float*)(smem + 32768);        // 32 x 132 f32 (16.9 KB)

    const int tid = threadIdx.x;
    const int bh = blockIdx.y;
    const int m0 = blockIdx.x * 128;
    const int lane = tid & 63, wid = tid >> 6;
    const int wm = wid >> 1, wn = wid & 1;
    const int lr = lane & 15, kg = lane >> 4;

    const __bf16* qbase = qws + ((size_t)bh * LSEQ + m0) * DDIM;
    const __bf16* kbase = kws + (size_t)bh * LSEQ * DDIM;

    const int row32 = tid >> 3, ch = tid & 7;
#pragma unroll
    for (int j = 0; j < 4; ++j) {
        int r = j * 32 + row32;
        int cs = ch ^ (r & 7);
        gl_lds16(qbase + (size_t)r * DDIM + cs * 8, (char*)Qs + j * 4096 + tid * 16);
        gl_lds16(kbase + (size_t)r * DDIM + cs * 8, (char*)Ks + j * 4096 + tid * 16);
    }
    __syncthreads();   // full drain: Q + K0 resident

    const int b = bh / HEADS;
    const int colb = (tid & 31) * 4;            // 0..124
    const int rrow = tid >> 5;                  // 0..7
    float* obase = out + (size_t)bh * LSEQ * LSEQ;

    for (int nt = 0; nt < 4; ++nt) {
        // ---- compute 128x128: D[n][m] ----
        f32x4 acc[4][4] = {};                   // [ai(n)][bi(m)]
#pragma unroll
        for (int ks = 0; ks < 2; ++ks) {
            bf16x8 af[4], qf[4];
#pragma unroll
            for (int ai = 0; ai < 4; ++ai) {
                int row = wn * 64 + ai * 16 + lr;
                int c = (kg + ks * 4) ^ (row & 7);
                af[ai] = *(bf16x8*)((char*)Ks + row * 128 + c * 16);
            }
#pragma unroll
            for (int bi = 0; bi < 4; ++bi) {
                int row = wm * 64 + bi * 16 + lr;
                int c = (kg + ks * 4) ^ (row & 7);
                qf[bi] = *(bf16x8*)((char*)Qs + row * 128 + c * 16);
            }
#pragma unroll
            for (int ai = 0; ai < 4; ++ai)
#pragma unroll
                for (int bi = 0; bi < 4; ++bi)
                    acc[ai][bi] = __builtin_amdgcn_mfma_f32_16x16x32_bf16(
                        af[ai], qf[bi], acc[ai][bi], 0, 0, 0);
        }
        ldsbar();   // all waves' Ks reads complete -> safe to overwrite Ks

        const int n0 = nt * 128;
        const float4 p4 = *(const float4*)&mask[b * LSEQ + n0 + colb];

        if (nt < 3) {   // prefetch next K tile (streams under the epilogue)
#pragma unroll
            for (int j = 0; j < 4; ++j) {
                int r = j * 32 + row32;
                int cs = ch ^ (r & 7);
                gl_lds16(kbase + (size_t)(n0 + 128 + r) * DDIM + cs * 8,
                         (char*)Ks + j * 4096 + tid * 16);
            }
        }

        // ---- epilogue: 4 rounds of 32-row LDS transpose -> coalesced stores ----
#pragma unroll
        for (int p = 0; p < 4; ++p) {
            ldsbar();   // Es free of prior-round readers
            if (wm == (p >> 1)) {
                const int bi0 = (p & 1) * 2;
#pragma unroll
                for (int bb = 0; bb < 2; ++bb) {
                    int bi = bi0 + bb;
                    int row = bb * 16 + lr;                // 0..31
#pragma unroll
                    for (int ai = 0; ai < 4; ++ai) {
                        int n = wn * 64 + ai * 16 + kg * 4;
                        *(f32x4*)&Es[row * 132 + n] = acc[ai][bi];
                    }
                }
            }
            ldsbar();   // writes visible
#pragma unroll
            for (int j = 0; j < 4; ++j) {
                int rloc = rrow + j * 8;                   // 0..31
                int m = m0 + p * 32 + rloc;
                f32x4 v = *(f32x4*)&Es[rloc * 132 + colb];
                int n = n0 + colb;
                f32x4 o;
                o[0] = (v[0] * p4.x - (1.0f - p4.x) * BIG_NEG
                        - ((m > n + 0) ? BIG_NEG : 0.0f)) * 0.125f;
                o[1] = (v[1] * p4.y - (1.0f - p4.y) * BIG_NEG
                        - ((m > n + 1) ? BIG_NEG : 0.0f)) * 0.125f;
                o[2] = (v[2] * p4.z - (1.0f - p4.z) * BIG_NEG
                        - ((m > n + 2) ? BIG_NEG : 0.0f)) * 0.125f;
                o[3] = (v[3] * p4.w - (1.0f - p4.w) * BIG_NEG
                        - ((m > n + 3) ? BIG_NEG : 0.0f)) * 0.125f;
                __builtin_nontemporal_store(o, (f32x4*)&obase[(size_t)m * LSEQ + n]);
            }
        }

        if (nt < 3) {
            // collect prefetch: 16 newest (this phase's NT stores) may float,
            // everything older (incl. the 8 gl_lds) must be done.
            asm volatile("s_waitcnt vmcnt(16) lgkmcnt(0)" ::: "memory");
            __builtin_amdgcn_s_barrier();
        }
    }
}

extern "C" void kernel_launch(void* const* d_in, const int* in_sizes, int n_in,
                              void* d_out, int out_size, void* d_ws, size_t ws_size,
                              hipStream_t stream) {
    const float* X    = (const float*)d_in[0];   // (16,512,768)
    const float* mask = (const float*)d_in[1];   // (16,512)
    const float* W    = (const float*)d_in[2];   // (768,1536)
    const float* bias = (const float*)d_in[3];   // (1536,)
    float* out = (float*)d_out;                  // (16,12,512,512)

    char* ws = (char*)d_ws;
    float*  cosT = (float*)ws;                            // 131072 B
    float*  sinT = (float*)(ws + 131072);                 // 131072 B
    __bf16* Wt   = (__bf16*)(ws + 262144);                // 2359296 B
    __bf16* Xb   = (__bf16*)(ws + 2621440);               // 12582912 B
    __bf16* qws  = (__bf16*)(ws + 2621440 + 12582912);    // 12582912 B
    __bf16* kws  = (__bf16*)(ws + 2621440 + 2*12582912);  // 12582912 B

    prep_k<<<4352, 256, 0, stream>>>(X, W, Xb, Wt, cosT, sinT);
    proj_rope_k<<<dim3(64, 12), 256, 0, stream>>>(Xb, Wt, bias, cosT, sinT, qws, kws);
    attn_k<<<dim3(4, 192), 256, 0, stream>>>(qws, kws, mask, out);
}

// Round 6
// 86.629 us; speedup vs baseline: 1.7209x; 1.0857x over previous
//
#include <hip/hip_runtime.h>
#include <stdint.h>

typedef float f32x4 __attribute__((ext_vector_type(4)));

#define HEADS 12
#define DDIM 64
#define LSEQ 512
#define HID 768
#define NOUT 1536
#define BIG_NEG 1000000000000.0f

__device__ __forceinline__ void gl_lds16(const void* g, void* l) {
    __builtin_amdgcn_global_load_lds(
        (const __attribute__((address_space(1))) void*)g,
        (__attribute__((address_space(3))) void*)l, 16, 0, 0);
}

// barrier that orders LDS only — does NOT drain vmcnt
__device__ __forceinline__ void ldsbar() {
    asm volatile("s_waitcnt lgkmcnt(0)" ::: "memory");
    __builtin_amdgcn_s_barrier();
}

__device__ __forceinline__ uint32_t pk4_fp8(float a, float b, float c, float d) {
    uint32_t v = __builtin_amdgcn_cvt_pk_fp8_f32(a, b, 0, false);
    v = __builtin_amdgcn_cvt_pk_fp8_f32(c, d, v, true);
    return v;
}

// ---- kernel 1 (fused prep): X->fp8, W->Wt fp8 transpose, RoPE tables --------
__global__ __launch_bounds__(256) void prep_k(
    const float* __restrict__ X, const float* __restrict__ W,
    uint8_t* __restrict__ Xq, uint8_t* __restrict__ Wtq,
    float* __restrict__ cosT, float* __restrict__ sinT) {

    int blk = blockIdx.x;
    if (blk < 3072) {
        size_t idx = ((size_t)blk * 256 + threadIdx.x) * 8;
        float4 f0 = *(const float4*)(X + idx);
        float4 f1 = *(const float4*)(X + idx + 4);
        uint2 p;
        p.x = pk4_fp8(f0.x, f0.y, f0.z, f0.w);
        p.y = pk4_fp8(f1.x, f1.y, f1.z, f1.w);
        *(uint2*)(Xq + idx) = p;
    } else if (blk < 4224) {
        __shared__ float Ls[32][33];
        int b2 = blk - 3072;
        int n0 = (b2 % 48) * 32, k0 = (b2 / 48) * 32;
        int tx = threadIdx.x & 31, ty = threadIdx.x >> 5;
#pragma unroll
        for (int rr = 0; rr < 4; ++rr) {
            int k = ty + rr * 8;
            Ls[k][tx] = W[(size_t)(k0 + k) * NOUT + n0 + tx];
        }
        __syncthreads();
        int n = threadIdx.x >> 3, c = threadIdx.x & 7;
        uint32_t w = pk4_fp8(Ls[4*c][n], Ls[4*c+1][n], Ls[4*c+2][n], Ls[4*c+3][n]);
        *(uint32_t*)(Wtq + (size_t)(n0 + n) * HID + k0 + c * 4) = w;
    } else {
        int idx = (blk - 4224) * 256 + threadIdx.x;
        int l = idx >> 6, d = idx & 63;
        int p = d >> 1;
        float inv = powf(10000.0f, (-2.0f * (float)p) / 64.0f);
        float ang = (float)l * inv;
        cosT[idx] = cosf(ang);
        sinT[idx] = sinf(ang);
    }
}

// ---------------- kernel 2: fp8 proj GEMM + bias + RoPE -> fp8 q/k slabs -----
// LDS tiles [128 rows][64B], 8B-slot swizzle s^=(row&6); gl_lds source chunk
// pre-swizzled c^=( (row>>1)&3 ). k-permutation identical for A/B -> cancels.
__global__ __launch_bounds__(256) void proj_rope_k(
    const uint8_t* __restrict__ Xq, const uint8_t* __restrict__ Wtq,
    const float* __restrict__ bias, const float* __restrict__ cosT,
    const float* __restrict__ sinT,
    uint8_t* __restrict__ qq, uint8_t* __restrict__ kq) {

    __shared__ __align__(16) uint8_t As[128 * 64];
    __shared__ __align__(16) uint8_t Bs[128 * 64];

    const int tid = threadIdx.x;
    const int m0 = blockIdx.x * 128, n0 = blockIdx.y * 128;
    const int lane = tid & 63, wid = tid >> 6;
    const int wm = wid >> 1, wn = wid & 1;
    const int lr = lane & 15, kg = lane >> 4;

    const int srow = tid >> 2, sc = tid & 3;

    f32x4 acc[4][4] = {};                 // [ai(n)][bi(m)]

    for (int k0 = 0; k0 < HID; k0 += 64) {
#pragma unroll
        for (int j = 0; j < 2; ++j) {
            int r = j * 64 + srow;
            int cs = sc ^ ((r >> 1) & 3);
            gl_lds16(Wtq + (size_t)(n0 + r) * HID + k0 + cs * 16,
                     Bs + j * 4096 + tid * 16);
            gl_lds16(Xq + (size_t)(m0 + r) * HID + k0 + cs * 16,
                     As + j * 4096 + tid * 16);
        }
        __syncthreads();
#pragma unroll
        for (int ks = 0; ks < 2; ++ks) {
            unsigned long long af[4], xf[4];
#pragma unroll
            for (int ai = 0; ai < 4; ++ai) {
                int row = wn * 64 + ai * 16 + lr;
                int sl = (ks * 4 + kg) ^ (row & 6);
                af[ai] = *(const unsigned long long*)(Bs + row * 64 + sl * 8);
            }
#pragma unroll
            for (int bi = 0; bi < 4; ++bi) {
                int row = wm * 64 + bi * 16 + lr;
                int sl = (ks * 4 + kg) ^ (row & 6);
                xf[bi] = *(const unsigned long long*)(As + row * 64 + sl * 8);
            }
#pragma unroll
            for (int ai = 0; ai < 4; ++ai)
#pragma unroll
                for (int bi = 0; bi < 4; ++bi)
                    acc[ai][bi] = __builtin_amdgcn_mfma_f32_16x16x32_fp8_fp8(
                        (long long)af[ai], (long long)xf[bi], acc[ai][bi], 0, 0, 0);
        }
        __syncthreads();
    }

    // ---- epilogue: bias + in-lane RoPE, pack fp8, 4B stores ----
#pragma unroll
    for (int ai = 0; ai < 4; ++ai) {
        int nb = n0 + wn * 64 + ai * 16 + kg * 4;  // 4-aligned
        int h = nb >> 7, d2 = nb & 127;
        int d = d2 & 63;
        uint8_t* dst = (d2 >= 64) ? kq : qq;
        float4 b4 = *(const float4*)&bias[nb];
#pragma unroll
        for (int bi = 0; bi < 4; ++bi) {
            int m = m0 + wm * 64 + bi * 16 + lr;
            int bidx = m >> 9, lpos = m & 511;
            float4 c4 = *(const float4*)&cosT[lpos * 64 + d];
            float4 s4 = *(const float4*)&sinT[lpos * 64 + d];
            float v0 = acc[ai][bi][0] + b4.x;
            float v1 = acc[ai][bi][1] + b4.y;
            float v2 = acc[ai][bi][2] + b4.z;
            float v3 = acc[ai][bi][3] + b4.w;
            float o0 = v0 * c4.x - v1 * s4.x;
            float o1 = v1 * c4.y + v0 * s4.y;
            float o2 = v2 * c4.z - v3 * s4.z;
            float o3 = v3 * c4.w + v2 * s4.w;
            uint32_t pw = pk4_fp8(o0, o1, o2, o3);
            *(uint32_t*)(dst + (((size_t)bidx * HEADS + h) * LSEQ + lpos) * DDIM + d) = pw;
        }
    }
}

// ---------------- kernel 3: fp8 QK^T + mask/tril/scale, 128m x 512n ----------
// Triangle fast-path: tiles fully below diagonal with pad==1 skip K/MFMA and
// are filled with the exact constant at kernel end (no sync interaction).
__global__ __launch_bounds__(256) void attn_k(
    const uint8_t* __restrict__ qq, const uint8_t* __restrict__ kq,
    const float* __restrict__ mask, float* __restrict__ out) {

    __shared__ __align__(16) uint8_t Qs[8192];
    __shared__ __align__(16) uint8_t Ks[8192];
    __shared__ __align__(16) float Es[32 * 132];
    __shared__ int wok[4];

    const int tid = threadIdx.x;
    const int bh = blockIdx.y;
    const int mtile = blockIdx.x;
    const int m0 = mtile * 128;
    const int lane = tid & 63, wid = tid >> 6;
    const int wm = wid >> 1, wn = wid & 1;
    const int lr = lane & 15, kg = lane >> 4;
    const int b = bh / HEADS;

    // ---- fast-path gate: all pads over the skipped cols must be exactly 1 ----
    int myok = 1;
    for (int c0 = tid; c0 < m0; c0 += 256)
        myok &= (mask[b * LSEQ + c0] == 1.0f) ? 1 : 0;
    unsigned long long bal = __ballot(myok);
    if (lane == 0) wok[wid] = (bal == ~0ull) ? 1 : 0;
    ldsbar();
    const int nstart = (wok[0] & wok[1] & wok[2] & wok[3]) ? mtile : 0;

    const uint8_t* qbase = qq + ((size_t)bh * LSEQ + m0) * DDIM;
    const uint8_t* kbase = kq + (size_t)bh * LSEQ * DDIM;

    const int srow = tid >> 2, sc = tid & 3;
#pragma unroll
    for (int j = 0; j < 2; ++j) {
        int r = j * 64 + srow;
        int cs = sc ^ ((r >> 1) & 3);
        gl_lds16(qbase + (size_t)r * DDIM + cs * 16, Qs + j * 4096 + tid * 16);
        gl_lds16(kbase + (size_t)(nstart * 128 + r) * DDIM + cs * 16,
                 Ks + j * 4096 + tid * 16);
    }
    __syncthreads();   // full drain: Q + K[nstart] resident

    const int colb = (tid & 31) * 4;            // 0..124
    const int rrow = tid >> 5;                  // 0..7
    float* obase = out + (size_t)bh * LSEQ * LSEQ;

    for (int nt = nstart; nt < 4; ++nt) {
        f32x4 acc[4][4] = {};                   // [ai(n)][bi(m)]
#pragma unroll
        for (int ks = 0; ks < 2; ++ks) {
            unsigned long long af[4], qf[4];
#pragma unroll
            for (int ai = 0; ai < 4; ++ai) {
                int row = wn * 64 + ai * 16 + lr;
                int sl = (ks * 4 + kg) ^ (row & 6);
                af[ai] = *(const unsigned long long*)(Ks + row * 64 + sl * 8);
            }
#pragma unroll
            for (int bi = 0; bi < 4; ++bi) {
                int row = wm * 64 + bi * 16 + lr;
                int sl = (ks * 4 + kg) ^ (row & 6);
                qf[bi] = *(const unsigned long long*)(Qs + row * 64 + sl * 8);
            }
#pragma unroll
            for (int ai = 0; ai < 4; ++ai)
#pragma unroll
                for (int bi = 0; bi < 4; ++bi)
                    acc[ai][bi] = __builtin_amdgcn_mfma_f32_16x16x32_fp8_fp8(
                        (long long)af[ai], (long long)qf[bi], acc[ai][bi], 0, 0, 0);
        }
        ldsbar();   // all waves' Ks reads complete -> safe to overwrite Ks

        const int n0 = nt * 128;
        const float4 p4 = *(const float4*)&mask[b * LSEQ + n0 + colb];

        if (nt < 3) {   // prefetch next K tile (streams under the epilogue)
#pragma unroll
            for (int j = 0; j < 2; ++j) {
                int r = j * 64 + srow;
                int cs = sc ^ ((r >> 1) & 3);
                gl_lds16(kbase + (size_t)((nt + 1) * 128 + r) * DDIM + cs * 16,
                         Ks + j * 4096 + tid * 16);
            }
        }

        // ---- epilogue: 4 rounds of 32-row LDS transpose -> coalesced stores ----
#pragma unroll
        for (int p = 0; p < 4; ++p) {
            ldsbar();   // Es free of prior-round readers
            if (wm == (p >> 1)) {
                const int bi0 = (p & 1) * 2;
#pragma unroll
                for (int bb = 0; bb < 2; ++bb) {
                    int bi = bi0 + bb;
                    int row = bb * 16 + lr;                // 0..31
#pragma unroll
                    for (int ai = 0; ai < 4; ++ai) {
                        int n = wn * 64 + ai * 16 + kg * 4;
                        *(f32x4*)&Es[row * 132 + n] = acc[ai][bi];
                    }
                }
            }
            ldsbar();   // writes visible
#pragma unroll
            for (int j = 0; j < 4; ++j) {
                int rloc = rrow + j * 8;                   // 0..31
                int m = m0 + p * 32 + rloc;
                f32x4 v = *(f32x4*)&Es[rloc * 132 + colb];
                int n = n0 + colb;
                f32x4 o;
                o[0] = (v[0] * p4.x - (1.0f - p4.x) * BIG_NEG
                        - ((m > n + 0) ? BIG_NEG : 0.0f)) * 0.125f;
                o[1] = (v[1] * p4.y - (1.0f - p4.y) * BIG_NEG
                        - ((m > n + 1) ? BIG_NEG : 0.0f)) * 0.125f;
                o[2] = (v[2] * p4.z - (1.0f - p4.z) * BIG_NEG
                        - ((m > n + 2) ? BIG_NEG : 0.0f)) * 0.125f;
                o[3] = (v[3] * p4.w - (1.0f - p4.w) * BIG_NEG
                        - ((m > n + 3) ? BIG_NEG : 0.0f)) * 0.125f;
                __builtin_nontemporal_store(o, (f32x4*)&obase[(size_t)m * LSEQ + n]);
            }
        }

        if (nt < 3) {
            // collect prefetch: 16 newest (this phase's NT stores) may float,
            // everything older (incl. the 2 gl_lds) must be done.
            asm volatile("s_waitcnt vmcnt(16) lgkmcnt(0)" ::: "memory");
            __builtin_amdgcn_s_barrier();
        }
    }

    // ---- fast-fill: constant region (pad==1, m>n for whole tile) ----
    const float CONSTV = (-BIG_NEG) * 0.125f;   // bit-exact vs ref chain
    f32x4 cv = {CONSTV, CONSTV, CONSTV, CONSTV};
    for (int nt2 = 0; nt2 < nstart; ++nt2) {
        int n = nt2 * 128 + colb;
#pragma unroll
        for (int p = 0; p < 4; ++p)
#pragma unroll
            for (int j = 0; j < 4; ++j) {
                int m = m0 + p * 32 + rrow + j * 8;
                __builtin_nontemporal_store(cv, (f32x4*)&obase[(size_t)m * LSEQ + n]);
            }
    }
}

extern "C" void kernel_launch(void* const* d_in, const int* in_sizes, int n_in,
                              void* d_out, int out_size, void* d_ws, size_t ws_size,
                              hipStream_t stream) {
    const float* X    = (const float*)d_in[0];   // (16,512,768)
    const float* mask = (const float*)d_in[1];   // (16,512)
    const float* W    = (const float*)d_in[2];   // (768,1536)
    const float* bias = (const float*)d_in[3];   // (1536,)
    float* out = (float*)d_out;                  // (16,12,512,512)

    char* ws = (char*)d_ws;
    float*   cosT = (float*)ws;                      // 131072 B
    float*   sinT = (float*)(ws + 131072);           // 131072 B
    uint8_t* Wtq  = (uint8_t*)(ws + 262144);         // 1179648 B
    uint8_t* Xq   = (uint8_t*)(ws + 1441792);        // 6291456 B
    uint8_t* qq   = (uint8_t*)(ws + 7733248);        // 6291456 B
    uint8_t* kq   = (uint8_t*)(ws + 14024704);       // 6291456 B

    prep_k<<<4352, 256, 0, stream>>>(X, W, Xq, Wtq, cosT, sinT);
    proj_rope_k<<<dim3(64, 12), 256, 0, stream>>>(Xq, Wtq, bias, cosT, sinT, qq, kq);
    attn_k<<<dim3(4, 192), 256, 0, stream>>>(qq, kq, mask, out);
}